// Round 14
// baseline (131.618 us; speedup 1.0000x reference)
//
#include <hip/hip_runtime.h>

constexpr int NTOK = 262144;
constexpr int D    = 64;   // CODE_DIM
constexpr int K    = 16;   // NUM_CODES
constexpr int TPB  = 256;
constexpr int ROW4 = D / 4;          // 16 float4 per token row
constexpr int TOKB = 64;             // tokens per block
constexpr int TPW  = 16;             // tokens per wave (4 lanes per token)

__global__ __launch_bounds__(TPB, 8) void quantizer_kernel(
    const float* __restrict__ x, const float* __restrict__ cb, float* __restrict__ out)
{
    // 16 KiB slab, 4 KiB per wave (WAVE-PRIVATE -> no __syncthreads anywhere;
    // same-wave LDS produce/consume is in-order, proven in R7).
    // Wave-local logical [tok][col] at phys tok*16 + (col ^ tok)  (float4 units).
    __shared__ float4 slab[TOKB * ROW4];

    const int tid  = threadIdx.x;
    const int lane = tid & 63;
    const int w    = __builtin_amdgcn_readfirstlane(tid >> 6);
    float4* sw     = slab + w * (TPW * ROW4);   // this wave's 256-float4 slice

    const int t = lane >> 2;    // token within wave [0,16)
    const int q = lane & 3;     // quarter of the row

    const float4* __restrict__ X4  = reinterpret_cast<const float4*>(x);
    const float4* __restrict__ CB4 = reinterpret_cast<const float4*>(cb);
    float4* __restrict__ out4      = reinterpret_cast<float4*>(out);

    // wave's contiguous region: 16 tokens * 16 float4 = 4 KiB
    const size_t wbase4 = ((size_t)blockIdx.x * TOKB + w * TPW) * ROW4;

    // ---- Phase 0: coalesced global read (kept in regs for residual) + swizzled stage ----
    float4 xs[4];
#pragma unroll
    for (int it = 0; it < 4; ++it) {
        const int i = it * 64 + lane;
        xs[it] = X4[wbase4 + i];
        const int row = i >> 4, col = i & 15;
        sw[(row << 4) + (col ^ row)] = xs[it];   // 2-way max -> free
    }
    // (no barrier: same-wave RAW through LDS, DS pipe in-order)

    // ---- Phase 1: own token's quarter from the wave slab ----
    float4 xr[4];
#pragma unroll
    for (int j = 0; j < 4; ++j)
        xr[j] = sw[(t << 4) + ((q * 4 + j) ^ t)];

    // ---- Phase 2: 16 partials, f32 fmaf chain per 16-elem quarter (bit-identical
    //      inner math to R9). Codebook per-lane (q varies) -> 4 KiB L1-resident,
    //      4 distinct addrs/instr, hidden under the fmaf chain. Overwrite the SAME
    //      slots this lane just consumed (each slot read by exactly its writer). ----
#pragma unroll
    for (int qq = 0; qq < 4; ++qq) {            // code quad
        float pq[4];
#pragma unroll
        for (int c = 0; c < 4; ++c) {
            const int k = 4 * qq + c;
            float pp = 0.f;
#pragma unroll
            for (int j = 0; j < 4; ++j) {
                float4 cc = CB4[k * ROW4 + q * 4 + j];
                float4 xv = xr[j];
                float d0 = xv.x - cc.x, d1 = xv.y - cc.y;
                float d2 = xv.z - cc.z, d3 = xv.w - cc.w;
                pp = fmaf(d0, d0, pp);
                pp = fmaf(d1, d1, pp);
                pp = fmaf(d2, d2, pp);
                pp = fmaf(d3, d3, pp);
            }
            pq[c] = pp;
        }
        sw[(t << 4) + ((q * 4 + qq) ^ t)] = make_float4(pq[0], pq[1], pq[2], pq[3]);
    }
    // (no barrier: cross-LANE, same-wave — in-order DS pipe)

    // ---- Phase 3: combine in f64, quarter order 0,1,2,3 (proven b-order);
    //      strict-< first-occurrence argmin, k ascending. All 4 lanes of a token
    //      read identical slots in identical order -> identical bidx. ----
    double best = 1e300;
    int bidx = 0;
#pragma unroll
    for (int qq = 0; qq < 4; ++qq) {
        float4 f0 = sw[(t << 4) + ((0 * 4 + qq) ^ t)];
        float4 f1 = sw[(t << 4) + ((1 * 4 + qq) ^ t)];
        float4 f2 = sw[(t << 4) + ((2 * 4 + qq) ^ t)];
        float4 f3 = sw[(t << 4) + ((3 * 4 + qq) ^ t)];
#define COMB(CMP, KK)                                                       \
        { double a = (double)f0.CMP; a += f1.CMP; a += f2.CMP; a += f3.CMP; \
          if (a < best) { best = a; bidx = 4 * qq + KK; } }
        COMB(x, 0) COMB(y, 1) COMB(z, 2) COMB(w, 3)
#undef COMB
    }

    // ---- onehot: wave region = 16 tokens * 4 float4 = 64 float4 -> ONE instr ----
    {
        const int tok = lane >> 2;                    // token within wave
        const int b   = __shfl(bidx, tok * 4);        // owner lane group's value
        const int sub = lane & 3;
        float4 v;
        v.x = (b == sub * 4 + 0) ? 1.f : 0.f;
        v.y = (b == sub * 4 + 1) ? 1.f : 0.f;
        v.z = (b == sub * 4 + 2) ? 1.f : 0.f;
        v.w = (b == sub * 4 + 3) ? 1.f : 0.f;
        out4[((size_t)blockIdx.x * TOKB + w * TPW) * (K / 4) + lane] = v;
    }

    // ---- residual: from xs regs (x read ONCE), coalesced wave-contiguous stores ----
    const size_t rbase = (size_t)NTOK * (K / 4) + wbase4;
#pragma unroll
    for (int it = 0; it < 4; ++it) {
        const int i   = it * 64 + lane;
        const int tok = i >> 4;                       // [0,16)
        const int b   = __shfl(bidx, tok * 4);
        float4 c  = CB4[b * ROW4 + (i & 15)];         // per-lane, L1-resident
        float4 xv = xs[it];
        float4 r;
        r.x = xv.x - c.x; r.y = xv.y - c.y;
        r.z = xv.z - c.z; r.w = xv.w - c.w;
        out4[rbase + i] = r;
    }
}

extern "C" void kernel_launch(void* const* d_in, const int* in_sizes, int n_in,
                              void* d_out, int out_size, void* d_ws, size_t ws_size,
                              hipStream_t stream) {
    const float* x  = (const float*)d_in[0];   // [262144, 64] fp32
    const float* cb = (const float*)d_in[1];   // [16, 64] fp32
    float* out = (float*)d_out;                // [N*16 onehot | N*64 residual] fp32

    quantizer_kernel<<<NTOK / TOKB, TPB, 0, stream>>>(x, cb, out);
}

// Round 15
// 29.033 us; speedup vs baseline: 4.5334x; 4.5334x over previous
//
#include <hip/hip_runtime.h>

constexpr int NTOK = 262144;
constexpr int D    = 64;   // CODE_DIM
constexpr int K    = 16;   // NUM_CODES
constexpr int TPB  = 256;
constexpr int ROW4 = D / 4;          // 16 float4 per token row
constexpr int TOKB = 64;             // tokens per block (4 threads/token)

__global__ __launch_bounds__(TPB, 8) void quantizer_kernel(
    const float* __restrict__ x, const float* __restrict__ cb, float* __restrict__ out)
{
    // 16 KiB slab, reused: x-transpose, then distance partials.
    // Logical [token][col4] at phys token*16 + (col ^ (token&15))  (float4 units).
    __shared__ float4 slab[TOKB * ROW4];

    const int tid = threadIdx.x;
    const int ln  = tid & 63;                                   // token within block
    const int w   = __builtin_amdgcn_readfirstlane(tid >> 6);   // wave id = quarter (SGPR)

    const float4* __restrict__ X4  = reinterpret_cast<const float4*>(x);
    const float4* __restrict__ CB4 = reinterpret_cast<const float4*>(cb);
    float4* __restrict__ out4      = reinterpret_cast<float4*>(out);

    const size_t blk4 = (size_t)blockIdx.x * TOKB * ROW4;

    // ---- Phase 0: the ONLY global read of x — fully coalesced (1 KiB/wave/instr).
    //      Keep in regs for the residual phase; also stage into swizzled slab. ----
    float4 xs[4];
#pragma unroll
    for (int it = 0; it < 4; ++it) {
        const int i = it * TPB + tid;
        xs[it] = X4[blk4 + i];
        const int t = i >> 4, c = i & 15;
        slab[(t << 4) + (c ^ (t & 15))] = xs[it];   // conflict-free (8/bank-group)
    }
    __syncthreads();   // barrier 1

    // ---- Phase 1: own token's quarter from LDS (wave w touches ONLY cols w*4..w*4+3) ----
    float4 xr[4];
#pragma unroll
    for (int j = 0; j < 4; ++j)
        xr[j] = slab[(ln << 4) + ((w * 4 + j) ^ (ln & 15))];

    // ---- Phase 2: 16 partials — f32 fmaf chain per 16-elem quarter, BIT-IDENTICAL
    //      to proven R5/R8 inner block. Write back into the SAME slots this wave
    //      just consumed (per-wave disjoint -> no barrier needed here). ----
#pragma unroll
    for (int q = 0; q < 4; ++q) {
        float pq[4];
#pragma unroll
        for (int c = 0; c < 4; ++c) {
            const int k = 4 * q + c;
            float pp = 0.f;
#pragma unroll
            for (int j = 0; j < 4; ++j) {
                float4 cc = CB4[k * ROW4 + w * 4 + j];   // SGPR-uniform -> s_load, K$-hot
                float4 xv = xr[j];
                float d0 = xv.x - cc.x, d1 = xv.y - cc.y;
                float d2 = xv.z - cc.z, d3 = xv.w - cc.w;
                pp = fmaf(d0, d0, pp);
                pp = fmaf(d1, d1, pp);
                pp = fmaf(d2, d2, pp);
                pp = fmaf(d3, d3, pp);
            }
            pq[c] = pp;
        }
        slab[(ln << 4) + ((w * 4 + q) ^ (ln & 15))] =
            make_float4(pq[0], pq[1], pq[2], pq[3]);
    }
    __syncthreads();   // barrier 2

    // ---- Phase 3: combine partials in f64, quarter order 0,1,2,3 == proven b-order;
    //      strict-< first-occurrence argmin, k ascending. ----
    double best = 1e300;
    int bidx = 0;
#pragma unroll
    for (int q = 0; q < 4; ++q) {
        float4 f0 = slab[(ln << 4) + ((0 * 4 + q) ^ (ln & 15))];
        float4 f1 = slab[(ln << 4) + ((1 * 4 + q) ^ (ln & 15))];
        float4 f2 = slab[(ln << 4) + ((2 * 4 + q) ^ (ln & 15))];
        float4 f3 = slab[(ln << 4) + ((3 * 4 + q) ^ (ln & 15))];
#define COMB(CMP, KK)                                                       \
        { double a = (double)f0.CMP; a += f1.CMP; a += f2.CMP; a += f3.CMP; \
          if (a < best) { best = a; bidx = 4 * q + KK; } }
        COMB(x, 0) COMB(y, 1) COMB(z, 2) COMB(w, 3)
#undef COMB
    }

    // ---- onehot: one coalesced float4 per thread (block region = 4 KiB) ----
    {
        const int tok = tid >> 2;                 // token in block [0,64)
        const int b   = __shfl(bidx, tok);        // identical across waves
        const int sub = tid & 3;
        float4 v;
        v.x = (b == sub * 4 + 0) ? 1.f : 0.f;
        v.y = (b == sub * 4 + 1) ? 1.f : 0.f;
        v.z = (b == sub * 4 + 2) ? 1.f : 0.f;
        v.w = (b == sub * 4 + 3) ? 1.f : 0.f;
        out4[(size_t)blockIdx.x * (TOKB * K / 4) + tid] = v;
    }

    // ---- residual: from xs regs (x read ONCE from HBM), coalesced stores ----
    const size_t rbase = (size_t)NTOK * (K / 4) + blk4;
#pragma unroll
    for (int it = 0; it < 4; ++it) {
        const int i   = it * TPB + tid;
        const int tok = i >> 4;
        const int b   = __shfl(bidx, tok);
        float4 c  = CB4[b * ROW4 + (tid & 15)];   // per-lane b, 4 KiB L1-resident
        float4 xv = xs[it];
        float4 r;
        r.x = xv.x - c.x; r.y = xv.y - c.y;
        r.z = xv.z - c.z; r.w = xv.w - c.w;
        out4[rbase + i] = r;
    }
}

extern "C" void kernel_launch(void* const* d_in, const int* in_sizes, int n_in,
                              void* d_out, int out_size, void* d_ws, size_t ws_size,
                              hipStream_t stream) {
    const float* x  = (const float*)d_in[0];   // [262144, 64] fp32
    const float* cb = (const float*)d_in[1];   // [16, 64] fp32
    float* out = (float*)d_out;                // [N*16 onehot | N*64 residual] fp32

    quantizer_kernel<<<NTOK / TOKB, TPB, 0, stream>>>(x, cb, out);
}